// Round 12
// baseline (121987.268 us; speedup 1.0000x reference)
//
#include <hip/hip_runtime.h>
#include <stdint.h>

typedef unsigned long long u64;
typedef uint32_t u32;

#define VOCAB 128
#define RD 128
#define DM 1024
#define NFF 6
#define BATCH 64
#define TSTEPS 512
#define NCH 32    // chains; chain c owns rows 2c, 2c+1
#define NST 6     // stages; stage s owns layer s (LDS-resident)

// ---------------------------------------------------------------------------
// ws layout (bytes):
//   [0,      786432)   ffbits [L][w][j] u64  (L<6, w<16, j<1024)
//   [786432, +2048)    ebits  [v][2]    u64
//   [788480, +2048)    headb  [v][2]    u64
//   [790528, +512)     losses [64]      double
//   [791040, +49152)   mb     [6][32][2][16] u64   stage-input masks
//   [840192, +6144)    flg    [6][32][2] u32, padded to 16 B each
// ---------------------------------------------------------------------------
#define OFF_EB    786432
#define OFF_HB    788480
#define OFF_LOSS  790528
#define OFF_MB    791040
#define OFF_FLG   840192

__device__ __forceinline__ void wait_ge(const u32* f, u32 target) {
    while (__hip_atomic_load(f, __ATOMIC_ACQUIRE, __HIP_MEMORY_SCOPE_AGENT) < target)
        __builtin_amdgcn_s_sleep(1);
}

// Pack ff sign bits: bit b of word (L,w,j) = (ff[L][w*64+b][j] < 0)  (1 => -1)
__global__ void pack_ff(const float* __restrict__ ff, u64* __restrict__ ffb) {
    int wid  = blockIdx.x * (blockDim.x >> 6) + (threadIdx.x >> 6); // 0..1535
    int lane = threadIdx.x & 63;
    int jt = wid & 15;
    int w  = (wid >> 4) & 15;
    int i  = wid >> 8;
    int j  = jt * 64 + lane;
    const float* src = ff + ((size_t)(i * DM) + w * 64) * DM + j;
    u64 word = 0;
#pragma unroll
    for (int b = 0; b < 64; ++b) {
        float v = src[(size_t)b * DM];
        word |= (u64)(v < 0.0f) << b;
    }
    ffb[((i * 16 + w) << 10) + j] = word;
}

__global__ void pack_small(const float* __restrict__ emb, const float* __restrict__ head,
                           u64* __restrict__ eb, u64* __restrict__ hb) {
    int tid = threadIdx.x; // 0..255
    if (tid < 128) {
        int v = tid;
        for (int wd = 0; wd < 2; ++wd) {
            u64 word = 0;
            for (int l = 0; l < 64; ++l)
                word |= (u64)(emb[v * RD + wd * 64 + l] < 0.0f) << l;
            eb[v * 2 + wd] = word;
        }
    } else {
        int v = tid - 128;
        for (int wd = 0; wd < 2; ++wd) {
            u64 word = 0;
            for (int l = 0; l < 64; ++l)
                word |= (u64)(head[(wd * 64 + l) * VOCAB + v] < 0.0f) << l;
            hb[v * 2 + wd] = word;
        }
    }
}

// 6-stage LDS-resident pipeline. 192 blocks x 1024 threads, 1 block/CU
// (128 KB LDS). blk = s*32 + c: consecutive stages differ by 32 == 0 mod 8
// -> same XCD, L2-local mask handoff. Thread tid owns column tid of layer s.
// Register demand ~40 VGPRs: nothing for the allocator to spill.
__global__ void __launch_bounds__(1024, 1)
brnn_stage(const int* __restrict__ tokens,
           const float* __restrict__ initial_lat,
           const float* __restrict__ thr_lat,
           const u64* __restrict__ ffb,
           const u64* __restrict__ eb,
           const u64* __restrict__ hb,
           u64* __restrict__ mb, u32* __restrict__ flg,
           double* __restrict__ losses)
{
    const int blk  = blockIdx.x;
    const int s    = blk >> 5;  // stage = layer
    const int c    = blk & 31;  // chain
    const int tid  = threadIdx.x;
    const int lane = tid & 63;
    const int wv   = tid >> 6;  // 0..15

    __shared__ __align__(16) u64 wlds[8][1024][2]; // layer s: 128 KB
    __shared__ __align__(16) u64 hx[2][16];
    __shared__ u64 hbL[2 * VOCAB];

    // --- one-time: stage layer into LDS (coalesced), thresholds, head bits ---
#pragma unroll
    for (int q = 0; q < 8; ++q) {
        wlds[q][tid][0] = ffb[((s * 16 + 2 * q)     << 10) + tid];
        wlds[q][tid][1] = ffb[((s * 16 + 2 * q + 1) << 10) + tid];
    }
    const int th   = (int)rintf(thr_lat[s * DM + tid]); // round-half-even
    const int cth  = ((DM - th) >> 1) + 1;              // bit(-1) <=> acc >= cth
    if (s == NST - 1 && tid < 2 * VOCAB) hbL[tid] = hb[tid];
    __syncthreads();

    double lacc0 = 0.0, lacc1 = 0.0;

    for (int t = 0; t < TSTEPS; ++t) {
#pragma unroll
        for (int ri = 0; ri < 2; ++ri) {
            const int r = 2 * c + ri;
            int tok = 0; u64 enew = 0;
            if (s == NST - 1) {
                tok = tokens[r * TSTEPS + t];              // uniform scalar load
                if (wv == 0 && lane < 2) enew = eb[tok * 2 + lane]; // prefetch
            }

            // --- acquire input h into hx[0] ---
            if (s == 0) {
                if (t == 0) {
                    u64 m = __ballot(initial_lat[tid] < 0.0f);
                    if (lane == 0) hx[0][wv] = m;
                } else {
                    wait_ge(&flg[((0 * NCH + c) * 2 + ri) << 2], (u32)t);
                    if (wv == 0 && lane < 16)
                        hx[0][lane] = mb[((0 * NCH + c) * 2 + ri) * 16 + lane];
                }
            } else {
                wait_ge(&flg[((s * NCH + c) * 2 + ri) << 2], (u32)(t + 1));
                if (wv == 0 && lane < 16)
                    hx[0][lane] = mb[((s * NCH + c) * 2 + ri) * 16 + lane];
            }
            __syncthreads();

            // --- the pass: 1024-bit XOR-popcount against LDS-resident layer ---
            const ulonglong2* hp = (const ulonglong2*)hx[0];
            int acc = 0;
#pragma unroll
            for (int q = 0; q < 8; ++q) {
                ulonglong2 hv = hp[q];                         // broadcast read
                const ulonglong2 wvv = *(const ulonglong2*)wlds[q][tid];
                acc += __popcll(hv.x ^ wvv.x) + __popcll(hv.y ^ wvv.y);
            }
            u64 m = __ballot(acc >= cth);

            if (s < NST - 1) {
                if (lane == 0) mb[(((s + 1) * NCH + c) * 2 + ri) * 16 + wv] = m;
                __syncthreads(); // drains vmcnt: mb stores visible
                if (tid == 0)
                    __hip_atomic_store(&flg[(((s + 1) * NCH + c) * 2 + ri) << 2],
                                       (u32)(t + 1), __ATOMIC_RELEASE,
                                       __HIP_MEMORY_SCOPE_AGENT);
            } else {
                // stage 5: h5 -> head/loss, build x_{t+1}, hand back to stage 0
                if (lane == 0) hx[1][wv] = m;
                __syncthreads();
                if (wv == 0) {
                    u64 ra = hx[1][14], rb = hx[1][15];
                    u64 h0a = hbL[lane * 2 + 0],        h0b = hbL[lane * 2 + 1];
                    u64 h1a = hbL[(lane + 64) * 2 + 0], h1b = hbL[(lane + 64) * 2 + 1];
                    int d0 = 128 - 2 * (__popcll(ra ^ h0a) + __popcll(rb ^ h0b));
                    int d1 = 128 - 2 * (__popcll(ra ^ h1a) + __popcll(rb ^ h1b));
                    float l0 = (float)d0 * (1.0f / 16.0f);
                    float l1 = (float)d1 * (1.0f / 16.0f);
                    float mx = fmaxf(l0, l1);
#pragma unroll
                    for (int sh = 32; sh >= 1; sh >>= 1) mx = fmaxf(mx, __shfl_xor(mx, sh));
                    float se = __expf(l0 - mx) + __expf(l1 - mx);
#pragma unroll
                    for (int sh = 32; sh >= 1; sh >>= 1) se += __shfl_xor(se, sh);
                    int   tl   = tok & 63;
                    float la   = __shfl(l0, tl);
                    float lb_  = __shfl(l1, tl);
                    float ltok = (tok >> 6) ? lb_ : la;
                    double dl = (double)(mx + __logf(se) - ltok);
                    if (ri == 0) lacc0 += dl; else lacc1 += dl;
                    // x_{t+1}: carry = h5 words 0..13, read = embed[tok] words 14,15
                    u64* mb0 = mb + ((0 * NCH + c) * 2 + ri) * 16;
                    if (lane < 14) mb0[lane] = hx[1][lane];
                    if (lane < 2)  mb0[14 + lane] = enew;
                }
                __syncthreads(); // drain wave0's mb stores
                if (tid == 0)
                    __hip_atomic_store(&flg[((0 * NCH + c) * 2 + ri) << 2],
                                       (u32)(t + 1), __ATOMIC_RELEASE,
                                       __HIP_MEMORY_SCOPE_AGENT);
            }
        }
    }

    if (s == NST - 1 && tid == 0) {
        losses[2 * c]     = lacc0;
        losses[2 * c + 1] = lacc1;
    }
}

__global__ void reduce_loss(const double* __restrict__ losses, float* __restrict__ out) {
    int lane = threadIdx.x; // 64 threads, 1 wave
    double v = losses[lane];
#pragma unroll
    for (int sh = 32; sh >= 1; sh >>= 1) v += __shfl_down(v, sh);
    if (lane == 0) out[0] = (float)(v * (1.0 / ((double)BATCH * (double)TSTEPS)));
}

extern "C" void kernel_launch(void* const* d_in, const int* in_sizes, int n_in,
                              void* d_out, int out_size, void* d_ws, size_t ws_size,
                              hipStream_t stream) {
    const int*   tokens  = (const int*)d_in[0];   // (64, 512) int32
    const float* initial = (const float*)d_in[1]; // (1024,)
    const float* embed   = (const float*)d_in[2]; // (128, 128)
    const float* ff      = (const float*)d_in[3]; // (6, 1024, 1024)
    const float* head    = (const float*)d_in[4]; // (128, 128)
    const float* thrl    = (const float*)d_in[5]; // (6, 1024)

    char* ws = (char*)d_ws;
    u64*    ffb    = (u64*)ws;
    u64*    eb     = (u64*)(ws + OFF_EB);
    u64*    hb     = (u64*)(ws + OFF_HB);
    double* losses = (double*)(ws + OFF_LOSS);
    u64*    mbuf   = (u64*)(ws + OFF_MB);
    u32*    flgs   = (u32*)(ws + OFF_FLG);

    // reset handshake flags every call (harness does not re-poison ws)
    hipMemsetAsync(ws + OFF_FLG, 0, 6144, stream);

    pack_ff<<<384, 256, 0, stream>>>(ff, ffb);
    pack_small<<<1, 256, 0, stream>>>(embed, head, eb, hb);
    brnn_stage<<<NST * NCH, 1024, 0, stream>>>(tokens, initial, thrl, ffb, eb, hb,
                                               mbuf, flgs, losses);
    reduce_loss<<<1, 64, 0, stream>>>(losses, (float*)d_out);
}

// Round 13
// 6304.808 us; speedup vs baseline: 19.3483x; 19.3483x over previous
//
#include <hip/hip_runtime.h>
#include <stdint.h>

typedef unsigned long long u64;
typedef u64 u64x2 __attribute__((ext_vector_type(2)));

#define VOCAB 128
#define RD 128
#define DM 1024
#define NFF 6
#define BATCH 64
#define TSTEPS 512
#define THR 256   // threads per block; thread owns cols c*256+tid, c=0..3

// ---------------------------------------------------------------------------
// ws layout (bytes):
//   [0, 786432)       ffs  [L][c][i][tid][2] u64  DMA-interleaved chunks:
//                     u64 idx = (((L*4+c)*8+i)*256+tid)*2 + s
//                     chunk (L,c) instr i delivers words (2i,2i+1) of
//                     column c*256+tid  -> consecutive lanes 16 B apart.
//   [786432, +2048)   ebits [v][2] u64
//   [788480, +2048)   headb [v][2] u64
//   [790528, +512)    losses [64] double
// ---------------------------------------------------------------------------
#define OFF_EB    786432
#define OFF_HB    788480
#define OFF_LOSS  790528

// Pack ff sign bits into the interleaved chunk layout.
// bit b of word (L,w,j) = (ff[L][w*64+b][j] < 0)  (1 => -1)
__global__ void pack_ff(const float* __restrict__ ff, u64* __restrict__ ffs) {
    int wid  = blockIdx.x * (blockDim.x >> 6) + (threadIdx.x >> 6); // 0..1535
    int lane = threadIdx.x & 63;
    int jt = wid & 15;
    int w  = (wid >> 4) & 15;  // word 0..15
    int L  = wid >> 8;         // layer
    int j  = jt * 64 + lane;   // column
    const float* src = ff + ((size_t)(L * DM) + w * 64) * DM + j;
    u64 word = 0;
#pragma unroll
    for (int b = 0; b < 64; ++b) {
        float v = src[(size_t)b * DM];
        word |= (u64)(v < 0.0f) << b;
    }
    int c = j >> 8, tid = j & 255, i = w >> 1, s = w & 1;
    ffs[((((L * 4 + c) * 8 + i) * 256 + tid) << 1) + s] = word;
}

// Pack embed rows and head columns (tiny).
__global__ void pack_small(const float* __restrict__ emb, const float* __restrict__ head,
                           u64* __restrict__ eb, u64* __restrict__ hb) {
    int tid = threadIdx.x; // 0..255
    if (tid < 128) {
        int v = tid;
        for (int wd = 0; wd < 2; ++wd) {
            u64 word = 0;
            for (int l = 0; l < 64; ++l)
                word |= (u64)(emb[v * RD + wd * 64 + l] < 0.0f) << l;
            eb[v * 2 + wd] = word;
        }
    } else {
        int v = tid - 128;
        for (int wd = 0; wd < 2; ++wd) {
            u64 word = 0;
            for (int l = 0; l < 64; ++l)
                word |= (u64)(head[(wd * 64 + l) * VOCAB + v] < 0.0f) << l;
            hb[v * 2 + wd] = word;
        }
    }
}

// Main recurrent kernel: one block (one CU) per batch row, 256 threads,
// 1 wave/SIMD (waves_per_eu(1,1) -> ~228-VGPR grant, proven r10).
// Layer 5 LDS-resident (128 KB); layers 0-4 streamed from L2 in 4 private
// chunks of 16 u64/thread (fully-coalesced dwordx4, no barriers in stream).
__global__ void
__attribute__((amdgpu_flat_work_group_size(THR, THR), amdgpu_waves_per_eu(1, 1)))
brnn_main(const int* __restrict__ tokens,
          const float* __restrict__ initial_lat,
          const float* __restrict__ thr_lat,
          const u64* __restrict__ ffs,
          const u64* __restrict__ eb,
          const u64* __restrict__ hb,
          double* __restrict__ losses)
{
    const int b    = blockIdx.x;
    const int tid  = threadIdx.x;
    const int lane = tid & 63;
    const int wv   = tid >> 6; // 0..3

    __shared__ __align__(16) u64 wlds[8][1024][2]; // layer 5: 128 KB
    __shared__ __align__(16) u64 hx[2][16];
    __shared__ u64 hbL[2 * VOCAB];

    const u64x2* wsrc = (const u64x2*)ffs;

    // --- one-time: stage layer 5 into LDS (from its interleaved chunks) ---
#pragma unroll
    for (int c = 0; c < 4; ++c)
#pragma unroll
        for (int i = 0; i < 8; ++i) {
            u64x2 v = wsrc[((5 * 4 + c) * 8 + i) * 256 + tid];
            wlds[i][c * 256 + tid][0] = v.x;
            wlds[i][c * 256 + tid][1] = v.y;
        }

    // thresholds -> popcount cutoffs:  bit(-1) <=> pre < thr  <=>  acc >= cthr
    int cthr[NFF][4];
#pragma unroll
    for (int L = 0; L < NFF; ++L)
#pragma unroll
        for (int c = 0; c < 4; ++c) {
            int th = (int)rintf(thr_lat[L * DM + c * 256 + tid]); // round-half-even
            cthr[L][c] = ((DM - th) >> 1) + 1;
        }

    if (tid < 2 * VOCAB) hbL[tid] = hb[tid];

    // --- init h = sign(initial_lat) into hx[0] ---
#pragma unroll
    for (int c = 0; c < 4; ++c) {
        u64 m = __ballot(initial_lat[c * 256 + tid] < 0.0f);
        if (lane == 0) hx[0][c * 4 + wv] = m;
    }
    __syncthreads();

    const int* toks = tokens + b * TSTEPS;
    double lacc = 0.0;

    for (int t = 0; t < TSTEPS; ++t) {
        int tok = toks[t]; // uniform -> scalar load

        // prefetch embed bits for the end-of-step splice (hides under 6 layers)
        u64 enew = 0;
        if (wv == 0 && lane < 2) enew = eb[tok * 2 + lane];

        int p = 0;
        // --- layers 0..4: streamed from L2, chunk = 1 private col/thread ---
        for (int L = 0; L < 5; ++L) {
            const ulonglong2* hp = (const ulonglong2*)hx[p];
#pragma unroll
            for (int c = 0; c < 4; ++c) {
                const u64x2* src = wsrc + ((L * 4 + c) * 8) * 256 + tid;
                u64x2 w0 = src[0 * 256], w1 = src[1 * 256], w2 = src[2 * 256],
                      w3 = src[3 * 256], w4 = src[4 * 256], w5 = src[5 * 256],
                      w6 = src[6 * 256], w7 = src[7 * 256];
                int acc = 0;
                ulonglong2 hv;
                hv = hp[0]; acc += __popcll(hv.x ^ w0.x) + __popcll(hv.y ^ w0.y);
                hv = hp[1]; acc += __popcll(hv.x ^ w1.x) + __popcll(hv.y ^ w1.y);
                hv = hp[2]; acc += __popcll(hv.x ^ w2.x) + __popcll(hv.y ^ w2.y);
                hv = hp[3]; acc += __popcll(hv.x ^ w3.x) + __popcll(hv.y ^ w3.y);
                hv = hp[4]; acc += __popcll(hv.x ^ w4.x) + __popcll(hv.y ^ w4.y);
                hv = hp[5]; acc += __popcll(hv.x ^ w5.x) + __popcll(hv.y ^ w5.y);
                hv = hp[6]; acc += __popcll(hv.x ^ w6.x) + __popcll(hv.y ^ w6.y);
                hv = hp[7]; acc += __popcll(hv.x ^ w7.x) + __popcll(hv.y ^ w7.y);
                u64 m = __ballot(acc >= cthr[L][c]);
                if (lane == 0) hx[p ^ 1][c * 4 + wv] = m;
            }
            __syncthreads();
            p ^= 1;
        }

        // --- layer 5: LDS-resident weights ---
        {
            const ulonglong2* hp = (const ulonglong2*)hx[p];
#pragma unroll
            for (int c = 0; c < 4; ++c) {
                int acc = 0;
#pragma unroll
                for (int q = 0; q < 8; ++q) {
                    ulonglong2 hv = hp[q]; // broadcast
                    const ulonglong2 wq = *(const ulonglong2*)wlds[q][c * 256 + tid];
                    acc += __popcll(hv.x ^ wq.x) + __popcll(hv.y ^ wq.y);
                }
                u64 m = __ballot(acc >= cthr[5][c]);
                if (lane == 0) hx[p ^ 1][c * 4 + wv] = m;
            }
            __syncthreads();
            p ^= 1; // p back to 0: final h in hx[0]
        }

        // --- head + log-softmax + loss + embed splice (wave 0 only) ---
        if (wv == 0) {
            u64 r0 = hx[0][14], r1 = hx[0][15];
            u64 h0a = hbL[lane * 2 + 0],        h0b = hbL[lane * 2 + 1];
            u64 h1a = hbL[(lane + 64) * 2 + 0], h1b = hbL[(lane + 64) * 2 + 1];
            int d0 = 128 - 2 * (__popcll(r0 ^ h0a) + __popcll(r1 ^ h0b));
            int d1 = 128 - 2 * (__popcll(r0 ^ h1a) + __popcll(r1 ^ h1b));
            float l0 = (float)d0 * (1.0f / 16.0f);
            float l1 = (float)d1 * (1.0f / 16.0f);
            float mx = fmaxf(l0, l1);
#pragma unroll
            for (int s = 32; s >= 1; s >>= 1) mx = fmaxf(mx, __shfl_xor(mx, s));
            float se = __expf(l0 - mx) + __expf(l1 - mx);
#pragma unroll
            for (int s = 32; s >= 1; s >>= 1) se += __shfl_xor(se, s);
            int   tl   = tok & 63;
            float la   = __shfl(l0, tl);
            float lb   = __shfl(l1, tl);
            float ltok = (tok >> 6) ? lb : la;
            lacc += (double)(mx + __logf(se) - ltok);
            // splice x_new read-part = sign(embed[tok]) into words 14,15
            if (lane < 2) hx[0][14 + lane] = enew;
        }
        __syncthreads();
    }

    if (tid == 0) losses[b] = lacc;
}

__global__ void reduce_loss(const double* __restrict__ losses, float* __restrict__ out) {
    int lane = threadIdx.x; // 64 threads, 1 wave
    double v = losses[lane];
#pragma unroll
    for (int s = 32; s >= 1; s >>= 1) v += __shfl_down(v, s);
    if (lane == 0) out[0] = (float)(v * (1.0 / ((double)BATCH * (double)TSTEPS)));
}

extern "C" void kernel_launch(void* const* d_in, const int* in_sizes, int n_in,
                              void* d_out, int out_size, void* d_ws, size_t ws_size,
                              hipStream_t stream) {
    const int*   tokens  = (const int*)d_in[0];   // (64, 512) int32
    const float* initial = (const float*)d_in[1]; // (1024,)
    const float* embed   = (const float*)d_in[2]; // (128, 128)
    const float* ff      = (const float*)d_in[3]; // (6, 1024, 1024)
    const float* head    = (const float*)d_in[4]; // (128, 128)
    const float* thrl    = (const float*)d_in[5]; // (6, 1024)

    char* ws = (char*)d_ws;
    u64*    ffs    = (u64*)ws;                 // 786432 B
    u64*    eb     = (u64*)(ws + OFF_EB);      // 2048 B
    u64*    hb     = (u64*)(ws + OFF_HB);      // 2048 B
    double* losses = (double*)(ws + OFF_LOSS); // 512 B

    pack_ff<<<384, 256, 0, stream>>>(ff, ffs);
    pack_small<<<1, 256, 0, stream>>>(embed, head, eb, hb);
    brnn_main<<<BATCH, THR, 0, stream>>>(tokens, initial, thrl, ffs, eb, hb, losses);
    reduce_loss<<<1, 64, 0, stream>>>(losses, (float*)d_out);
}